// Round 4
// baseline (1915.732 us; speedup 1.0000x reference)
//
#include <hip/hip_runtime.h>
#include <hip/hip_bf16.h>
#include <math.h>

#define Bb 32
#define Cc 512
#define HW 3136        // 56*56
#define HW4 784        // HW/4
#define G  32
#define GS 16
#define Nn (Bb*HW)     // 100352
#define EPSF 1e-3f
#define TRI 136        // 16*17/2
#define STATS (TRI+GS) // 152
#define PART_STRIDE 272 // 256 full-C entries + 16 channel sums

// stats tiling
#define T_POS 448      // positions per LDS tile (3136 = 7*448)
#define T4 112         // T_POS/4
#define NTILE 7
#define PADROW 452     // LDS row stride (floats)
#define PPG 28         // positions per position-group (448/16)
#define PPG4 7

typedef float floatx4 __attribute__((ext_vector_type(4)));

// ---------------- Kernel 1: per-(b,g) full C = x x^T partials + channel sums ----------------
// Each block: one (b,g). LDS-staged 16x448 tiles; thread t owns 4x4 C-subtile
// (tileid = t&15) over position-group pg = t>>4. ~60 VGPRs -> 4 waves/EU.
__global__ __launch_bounds__(256, 4) void stats_kernel(const float* __restrict__ x,
                                                       float* __restrict__ part) {
    const int b = blockIdx.x >> 5;     // /G
    const int g = blockIdx.x & 31;     // %G
    const int tid = threadIdx.x;
    const int tileid = tid & 15;
    const int pg = tid >> 4;
    const int ti = tileid >> 2;
    const int tj = tileid & 3;
    const bool diag = (ti == tj);

    __shared__ float lds[GS * PADROW];   // 28,928 B; reused for reduction

    const size_t boff4 = ((size_t)b * Cc + (size_t)g * GS) * HW4;
    const floatx4* __restrict__ x4 = (const floatx4*)x + boff4;

    float acc[16];
    float ssum[4];
#pragma unroll
    for (int i = 0; i < 16; i++) acc[i] = 0.f;
#pragma unroll
    for (int i = 0; i < 4; i++) ssum[i] = 0.f;

    for (int t = 0; t < NTILE; t++) {
        __syncthreads();
        // stage 16x448 tile: 1792 float4, 7 per thread, coalesced
#pragma unroll
        for (int r = 0; r < 7; r++) {
            int f = tid + 256 * r;           // 0..1791
            int c = f / T4;
            int i4 = f - c * T4;
            floatx4 v = x4[(size_t)c * HW4 + t * T4 + i4];
            *(floatx4*)&lds[c * PADROW + i4 * 4] = v;
        }
        __syncthreads();

        const float* arow = &lds[(ti * 4) * PADROW + pg * PPG];
        const float* brow = &lds[(tj * 4) * PADROW + pg * PPG];
#pragma unroll
        for (int q = 0; q < PPG4; q++) {
            floatx4 a[4], bv[4];
#pragma unroll
            for (int k = 0; k < 4; k++) a[k]  = *(const floatx4*)&arow[k * PADROW + q * 4];
#pragma unroll
            for (int k = 0; k < 4; k++) bv[k] = *(const floatx4*)&brow[k * PADROW + q * 4];
#pragma unroll
            for (int r = 0; r < 4; r++)
#pragma unroll
                for (int c2 = 0; c2 < 4; c2++) {
                    acc[r * 4 + c2] += a[r].x * bv[c2].x + a[r].y * bv[c2].y
                                     + a[r].z * bv[c2].z + a[r].w * bv[c2].w;
                }
            if (diag) {
#pragma unroll
                for (int k = 0; k < 4; k++)
                    ssum[k] += a[k].x + a[k].y + a[k].z + a[k].w;
            }
        }
    }

    __syncthreads();
    // reduce over 16 position-groups through LDS (reuse buffer)
    float* redC = lds;            // [256 entries][17]
    float* redS = lds + 256 * 17; // [16 ch][17]
#pragma unroll
    for (int e = 0; e < 16; e++)
        redC[(tileid * 16 + e) * 17 + pg] = acc[e];
    if (diag) {
#pragma unroll
        for (int k = 0; k < 4; k++)
            redS[(ti * 4 + k) * 17 + pg] = ssum[k];
    }
    __syncthreads();

    // thread tid owns C entry (i,j)
    const int i = tid >> 4, j = tid & 15;
    const int entry = ((i >> 2) * 4 + (j >> 2)) * 16 + (i & 3) * 4 + (j & 3);
    float v = 0.f;
#pragma unroll
    for (int p2 = 0; p2 < 16; p2++) v += redC[entry * 17 + p2];
    float* pout = part + ((size_t)g * Bb + b) * PART_STRIDE;
    pout[tid] = v;
    if (tid < GS) {
        float sv = 0.f;
#pragma unroll
        for (int p2 = 0; p2 < 16; p2++) sv += redS[tid * 17 + p2];
        pout[256 + tid] = sv;
    }
}

// ---------------- Kernel 2: reduce partials, Cholesky, invert, pack L^-1 + bias ----------------
__global__ __launch_bounds__(64) void solve_kernel(const float* __restrict__ part,
                                                   float* __restrict__ wl) {
    const int g = blockIdx.x;
    const int t = threadIdx.x;

    __shared__ float st[PART_STRIDE];
    __shared__ float cov[GS][GS];
    __shared__ float L[GS][GS];
    __shared__ float Li[GS][GS];
    __shared__ float m[GS];

    for (int k = t; k < PART_STRIDE; k += 64) {
        float acc = 0.f;
#pragma unroll
        for (int b = 0; b < Bb; b++)
            acc += part[((size_t)g * Bb + b) * PART_STRIDE + k];
        st[k] = acc;
    }
    __syncthreads();

    if (t < GS) m[t] = st[256 + t] * (1.0f / (float)Nn);
    __syncthreads();

    for (int e = t; e < GS * GS; e += 64) {
        int i = e >> 4, j = e & 15;
        float cv = st[i * 16 + j] * (1.0f / (float)Nn) - m[i] * m[j];
        cv *= (1.0f - EPSF);
        if (i == j) cv += EPSF;
        cov[i][j] = cv;
    }
    __syncthreads();

    if (t == 0) {
        for (int k = 0; k < GS; k++) {
            float d = cov[k][k];
            for (int r = 0; r < k; r++) d -= L[k][r] * L[k][r];
            d = sqrtf(d);
            L[k][k] = d;
            float inv = 1.0f / d;
            for (int i = k + 1; i < GS; i++) {
                float v = cov[i][k];
                for (int r = 0; r < k; r++) v -= L[i][r] * L[k][r];
                L[i][k] = v * inv;
            }
        }
    }
    __syncthreads();

    if (t < GS) {
        const int j = t;
        for (int i = 0; i < GS; i++) Li[i][j] = 0.f;
        for (int i = j; i < GS; i++) {
            float v = (i == j) ? 1.f : 0.f;
            for (int k = j; k < i; k++) v -= L[i][k] * Li[k][j];
            Li[i][j] = v / L[i][i];
        }
    }
    __syncthreads();

    float* wg = wl + (size_t)g * STATS;
    for (int e = t; e < GS * GS; e += 64) {
        int i = e >> 4, j = e & 15;
        if (j <= i) wg[i * (i + 1) / 2 + j] = Li[i][j];
    }
    if (t < GS) {
        float bias = 0.f;
        for (int j = 0; j <= t; j++) bias += Li[t][j] * m[j];
        wg[TRI + t] = bias;
    }
}

// ---------------- Kernel 3: out = L^-1 x - bias; weights in LDS (broadcast) ----------------
// o[16] float4 accumulators in regs (~64), weights re-read per position from LDS;
// __launch_bounds__(256,3) caps VGPRs so the compiler can't hoist all 152 weights.
__global__ __launch_bounds__(256, 3) void apply_kernel(const float* __restrict__ x,
                                                       const float* __restrict__ wl,
                                                       float* __restrict__ out) {
    const int b = blockIdx.x >> 5;
    const int g = blockIdx.x & 31;
    const int tid = threadIdx.x;

    __shared__ float w[TRI];
    __shared__ float bias[GS];
    const float* __restrict__ wg = wl + (size_t)g * STATS;
    if (tid < TRI) w[tid] = wg[tid];
    if (tid >= TRI && tid < STATS) bias[tid - TRI] = wg[tid];
    __syncthreads();

    const size_t boff4 = ((size_t)b * Cc + (size_t)g * GS) * HW4;
    const floatx4* __restrict__ xb = (const floatx4*)x + boff4;
    floatx4* __restrict__ ob = (floatx4*)out + boff4;

    for (int p = tid; p < HW4; p += 256) {
        floatx4 o[GS];
#pragma unroll
        for (int i = 0; i < GS; i++) o[i] = (floatx4)(-bias[i]);
#pragma unroll
        for (int j = 0; j < GS; j++) {
            floatx4 v = xb[(size_t)j * HW4 + p];
#pragma unroll
            for (int i = j; i < GS; i++) o[i] += w[i * (i + 1) / 2 + j] * v;
        }
#pragma unroll
        for (int i = 0; i < GS; i++)
            __builtin_nontemporal_store(o[i], &ob[(size_t)i * HW4 + p]);
    }
}

extern "C" void kernel_launch(void* const* d_in, const int* in_sizes, int n_in,
                              void* d_out, int out_size, void* d_ws, size_t ws_size,
                              hipStream_t stream) {
    const float* x = (const float*)d_in[0];
    float* out = (float*)d_out;

    float* part = (float*)d_ws;                              // G*Bb*PART_STRIDE floats
    float* wl = part + (size_t)G * Bb * PART_STRIDE;         // G*STATS floats

    stats_kernel<<<Bb * G, 256, 0, stream>>>(x, part);
    solve_kernel<<<G, 64, 0, stream>>>(part, wl);
    apply_kernel<<<Bb * G, 256, 0, stream>>>(x, wl, out);
}